// Round 1
// baseline (113.492 us; speedup 1.0000x reference)
//
#include <hip/hip_runtime.h>

#define B_ 16
#define C_ 256
#define P_ 2048

typedef __attribute__((ext_vector_type(8))) short short8;
typedef __attribute__((ext_vector_type(4))) float floatx4;

// round-to-nearest-even fp32 -> bf16 (inputs are finite random normals)
__device__ inline short f2bf(float v) {
  union { float f; unsigned u; } c; c.f = v;
  unsigned r = c.u + 0x7fffu + ((c.u >> 16) & 1u);
  return (short)(r >> 16);
}

#define GLOAD_LDS16(g, l)                                          \
  __builtin_amdgcn_global_load_lds(                                \
      (const __attribute__((address_space(1))) void*)(g),          \
      (__attribute__((address_space(3))) void*)(l), 16, 0, 0)

// ---------------- kernel 1: transpose + fp32->bf16 convert ----------------
// x[b][c][p] (p contiguous) -> Xt[b][p][c] (c contiguous)
__global__ void k_transpose(const float* __restrict__ x, short* __restrict__ Xt) {
  __shared__ float t[32][33];
  const int p0 = blockIdx.x * 32, c0 = blockIdx.y * 32, b = blockIdx.z;
  const float* xb = x + (size_t)b * C_ * P_;
  short* xtb = Xt + (size_t)b * P_ * C_;
  const int tx = threadIdx.x, ty = threadIdx.y;
#pragma unroll
  for (int i = 0; i < 4; ++i)
    t[ty + i * 8][tx] = xb[(size_t)(c0 + ty + i * 8) * P_ + p0 + tx];
  __syncthreads();
  // write phase: flat tid; each thread writes 4 consecutive bf16 (8B) -> fully coalesced
  const int tid = ty * 32 + tx;
  const int r = tid >> 3;        // local p row 0..31
  const int ch = tid & 7;        // c chunk, 4 shorts each
  short4 v;
  v.x = f2bf(t[ch * 4 + 0][r]);
  v.y = f2bf(t[ch * 4 + 1][r]);
  v.z = f2bf(t[ch * 4 + 2][r]);
  v.w = f2bf(t[ch * 4 + 3][r]);
  *reinterpret_cast<short4*>(&xtb[(size_t)(p0 + r) * C_ + c0 + ch * 4]) = v;
}

// ---------------- kernel 2: fp32 norms ----------------
__global__ void k_norms(const float* __restrict__ x, float* __restrict__ nrm) {
  const int b = blockIdx.y;
  const int p = blockIdx.x * 64 + threadIdx.x;
  const float* xb = x + (size_t)b * C_ * P_;
  float s = 0.f;
#pragma unroll 8
  for (int c = 0; c < C_; ++c) {
    float v = xb[(size_t)c * P_ + p];
    s += v * v;
  }
  nrm[b * P_ + p] = sqrtf(s);
}

// ---------------- kernel 3: Gram GEMM + normalize epilogue ----------------
// C[p][q] = sum_k Xt[p][k]*Xt[q][k]  (both operands from the same matrix)
#define BM 128
#define BN 128
#define BK 32

__global__ __launch_bounds__(256, 2) void k_gemm(const short* __restrict__ Xt,
                                                 const float* __restrict__ nrm,
                                                 float* __restrict__ out) {
  const int b = blockIdx.y;
  const int ntn = P_ / BN;                 // 16
  const int tm = blockIdx.x / ntn;
  const int tn = blockIdx.x % ntn;
  const int p0 = tm * BM;
  const int q0 = tn * BN;

  const short* Xb = Xt + (size_t)b * P_ * C_;

  __shared__ __align__(16) short As[BM * BK];  // [128][32] k-contiguous, 8KB
  __shared__ __align__(16) short Bs[BN * BK];

  const int tid  = threadIdx.x;
  const int lane = tid & 63;
  const int wid  = tid >> 6;     // 0..3
  const int wrow = wid >> 1;     // 0..1 -> 64-row band
  const int wcol = wid & 1;      // 0..1 -> 64-col band

  floatx4 acc[4][4];
#pragma unroll
  for (int i = 0; i < 4; ++i)
#pragma unroll
    for (int j = 0; j < 4; ++j)
      acc[i][j] = (floatx4){0.f, 0.f, 0.f, 0.f};

  const int K2 = C_ * 2;  // row stride in bytes (512)

  for (int kt = 0; kt < C_ / BK; ++kt) {
    __syncthreads();  // previous iteration's LDS reads complete
    const int kb = kt * (BK * 2);  // byte offset of this K-slab within a row
#pragma unroll
    for (int j = 0; j < 2; ++j) {
      const int chunk = j * 4 + wid;            // 0..7 (1KB each)
      const int f = chunk * 1024 + lane * 16;   // flat byte within 8KB tile
      const int row = f >> 6;                   // 64B per row (32 bf16)
      const int inrow = f & 63;
      const char* ga = (const char*)Xb + (size_t)(p0 + row) * K2 + kb + inrow;
      const char* gb = (const char*)Xb + (size_t)(q0 + row) * K2 + kb + inrow;
      GLOAD_LDS16(ga, (char*)As + chunk * 1024);
      GLOAD_LDS16(gb, (char*)Bs + chunk * 1024);
    }
    __syncthreads();  // drains vmcnt before barrier -> tiles visible

    short8 af[4], bf[4];
#pragma unroll
    for (int mi = 0; mi < 4; ++mi) {
      const int r = wrow * 64 + mi * 16 + (lane & 15);
      af[mi] = *reinterpret_cast<const short8*>(&As[r * BK + (lane >> 4) * 8]);
    }
#pragma unroll
    for (int ni = 0; ni < 4; ++ni) {
      const int r = wcol * 64 + ni * 16 + (lane & 15);
      bf[ni] = *reinterpret_cast<const short8*>(&Bs[r * BK + (lane >> 4) * 8]);
    }
#pragma unroll
    for (int mi = 0; mi < 4; ++mi)
#pragma unroll
      for (int ni = 0; ni < 4; ++ni)
        acc[mi][ni] = __builtin_amdgcn_mfma_f32_16x16x32_bf16(af[mi], bf[ni], acc[mi][ni], 0, 0, 0);
  }

  // epilogue: divide by max(norm_p * norm_q, eps), diag = 1
  const int col_l  = lane & 15;
  const int row_g4 = (lane >> 4) * 4;
  const float* nb = nrm + (size_t)b * P_;
  float* ob = out + (size_t)b * P_ * P_;
#pragma unroll
  for (int ni = 0; ni < 4; ++ni) {
    const int qc = q0 + wcol * 64 + ni * 16 + col_l;
    const float nq = nb[qc];
#pragma unroll
    for (int mi = 0; mi < 4; ++mi) {
#pragma unroll
      for (int r = 0; r < 4; ++r) {
        const int pr = p0 + wrow * 64 + mi * 16 + row_g4 + r;
        const float np = nb[pr];
        const float den = fmaxf(np * nq, 1e-8f);
        float v = acc[mi][ni][r] / den;
        if (pr == qc) v = 1.0f;
        ob[(size_t)pr * P_ + qc] = v;
      }
    }
  }
}

extern "C" void kernel_launch(void* const* d_in, const int* in_sizes, int n_in,
                              void* d_out, int out_size, void* d_ws, size_t ws_size,
                              hipStream_t stream) {
  const float* x = (const float*)d_in[0];
  float* out = (float*)d_out;

  // workspace layout: Xt bf16 [16][2048][256] = 16 MB, then norms fp32 [16][2048] = 128 KB
  short* Xt = (short*)d_ws;
  float* nrm = (float*)((char*)d_ws + (size_t)B_ * P_ * C_ * sizeof(short));

  k_transpose<<<dim3(P_ / 32, C_ / 32, B_), dim3(32, 8), 0, stream>>>(x, Xt);
  k_norms<<<dim3(P_ / 64, B_), 64, 0, stream>>>(x, nrm);
  k_gemm<<<dim3((P_ / BM) * (P_ / BN), B_), 256, 0, stream>>>(Xt, nrm, out);
}

// Round 2
// 99.525 us; speedup vs baseline: 1.1403x; 1.1403x over previous
//
#include <hip/hip_runtime.h>

#define B_ 16
#define C_ 256
#define P_ 2048
#define BK 32
#define NT_OFF 120  // 16*15/2 strict-upper tiles per batch

typedef __attribute__((ext_vector_type(8))) short short8;
typedef __attribute__((ext_vector_type(4))) float floatx4;

// round-to-nearest-even fp32 -> bf16 (inputs are finite random normals)
__device__ inline short f2bf(float v) {
  union { float f; unsigned u; } c; c.f = v;
  unsigned r = c.u + 0x7fffu + ((c.u >> 16) & 1u);
  return (short)(r >> 16);
}

#define GLOAD_LDS16(g, l)                                          \
  __builtin_amdgcn_global_load_lds(                                \
      (const __attribute__((address_space(1))) void*)(g),          \
      (__attribute__((address_space(3))) void*)(l), 16, 0, 0)

// ---------------- kernel 1: transpose + fp32->bf16 convert + norm^2 ----------------
// x[b][c][p] -> Xt[b][p][c]; nrm2[b][p] += partial sum of squares (atomic, fp32)
__global__ void k_transpose(const float* __restrict__ x, short* __restrict__ Xt,
                            float* __restrict__ nrm2) {
  __shared__ float t[32][33];
  __shared__ float red[8][32];
  const int p0 = blockIdx.x * 32, c0 = blockIdx.y * 32, b = blockIdx.z;
  const float* xb = x + (size_t)b * C_ * P_;
  short* xtb = Xt + (size_t)b * P_ * C_;
  const int tx = threadIdx.x, ty = threadIdx.y;
  float s = 0.f;
#pragma unroll
  for (int i = 0; i < 4; ++i) {
    float v = xb[(size_t)(c0 + ty + i * 8) * P_ + p0 + tx];
    t[ty + i * 8][tx] = v;
    s += v * v;
  }
  red[ty][tx] = s;
  __syncthreads();
  const int tid = ty * 32 + tx;
  const int r = tid >> 3;   // local p row 0..31
  const int ch = tid & 7;   // c chunk of 4 shorts
  short4 v;
  v.x = f2bf(t[ch * 4 + 0][r]);
  v.y = f2bf(t[ch * 4 + 1][r]);
  v.z = f2bf(t[ch * 4 + 2][r]);
  v.w = f2bf(t[ch * 4 + 3][r]);
  *reinterpret_cast<short4*>(&xtb[(size_t)(p0 + r) * C_ + c0 + ch * 4]) = v;
  if (tid < 32) {
    float ns = 0.f;
#pragma unroll
    for (int j = 0; j < 8; ++j) ns += red[j][tid];
    atomicAdd(&nrm2[b * P_ + p0 + tid], ns);
  }
}

// ---------------- kernel 2: symmetric Gram GEMM + normalize epilogue ----------------
__global__ __launch_bounds__(256, 3) void k_gemm(const short* __restrict__ Xt,
                                                 const float* __restrict__ nrm2,
                                                 float* __restrict__ out) {
  const int b = blockIdx.y;
  int t = blockIdx.x;
  int tm, tn;
  if (t < NT_OFF) {  // strict upper: heavy (2-write) blocks dispatched first
    int rem = t, len = 15;
    tm = 0;
    while (rem >= len) { rem -= len; --len; ++tm; }
    tn = tm + 1 + rem;
  } else {
    tm = tn = t - NT_OFF;
  }
  const int p0 = tm * 128, q0 = tn * 128;
  const short* Xb = Xt + (size_t)b * P_ * C_;

  __shared__ __align__(16) short As[2][128 * BK];  // 8 KB each buf
  __shared__ __align__(16) short Bs[2][128 * BK];

  const int tid = threadIdx.x;
  const int lane = tid & 63;
  const int wid = tid >> 6;
  const int wrow = wid >> 1;  // 64-row band of p
  const int wcol = wid & 1;   // 64-col band of q

  floatx4 acc[4][4];
#pragma unroll
  for (int i = 0; i < 4; ++i)
#pragma unroll
    for (int j = 0; j < 4; ++j) acc[i][j] = (floatx4){0.f, 0.f, 0.f, 0.f};

  const int K2 = C_ * 2;  // bf16 row stride bytes

  auto STAGE = [&](int buf, int kt) {
    const int kb = kt * (BK * 2);
#pragma unroll
    for (int j = 0; j < 2; ++j) {
      const int chunk = j * 4 + wid;           // 0..7, wave-uniform
      const int f = chunk * 1024 + lane * 16;  // flat byte in 8KB tile
      const int row = f >> 6;                  // 64 B per row
      const int inrow = f & 63;
      GLOAD_LDS16((const char*)Xb + (size_t)(p0 + row) * K2 + kb + inrow,
                  (char*)(&As[buf][0]) + chunk * 1024);
      GLOAD_LDS16((const char*)Xb + (size_t)(q0 + row) * K2 + kb + inrow,
                  (char*)(&Bs[buf][0]) + chunk * 1024);
    }
  };

  STAGE(0, 0);  // prologue: 4 loads in flight

  for (int kt = 0; kt < C_ / BK; ++kt) {
    const int cur = kt & 1;
    if (kt < C_ / BK - 1) {
      STAGE(cur ^ 1, kt + 1);                          // 4 more in flight
      asm volatile("s_waitcnt vmcnt(4)" ::: "memory"); // cur tile landed; next stays in flight
    } else {
      asm volatile("s_waitcnt vmcnt(0)" ::: "memory");
    }
    __builtin_amdgcn_s_barrier();

    short8 af[4], bf[4];
#pragma unroll
    for (int mi = 0; mi < 4; ++mi) {
      const int r = wrow * 64 + mi * 16 + (lane & 15);
      af[mi] = *reinterpret_cast<const short8*>(&As[cur][r * BK + (lane >> 4) * 8]);
    }
#pragma unroll
    for (int ni = 0; ni < 4; ++ni) {
      const int r = wcol * 64 + ni * 16 + (lane & 15);
      bf[ni] = *reinterpret_cast<const short8*>(&Bs[cur][r * BK + (lane >> 4) * 8]);
    }
    // swapped operands: D[row=q][col=p] -> acc vector runs along q => float4 row stores
#pragma unroll
    for (int mi = 0; mi < 4; ++mi)
#pragma unroll
      for (int ni = 0; ni < 4; ++ni)
        acc[mi][ni] = __builtin_amdgcn_mfma_f32_16x16x32_bf16(bf[ni], af[mi], acc[mi][ni], 0, 0, 0);

    __builtin_amdgcn_s_barrier();  // all waves done reading cur before it is restaged
  }

  // ---- epilogue: v = dot * rcp(np) * rcp(nq); diag=1; write tile (+mirror) ----
  const float* n2 = nrm2 + (size_t)b * P_;
  float* ob = out + (size_t)b * P_ * P_;
  const int cl = lane & 15, ch4 = (lane >> 4) * 4;

  float rnp[4];
#pragma unroll
  for (int mi = 0; mi < 4; ++mi) {
    const int pr = p0 + wrow * 64 + mi * 16 + cl;
    rnp[mi] = __builtin_amdgcn_rcpf(fmaxf(sqrtf(n2[pr]), 1e-4f));
  }
  float rnq[4][4];
  int qb[4];
#pragma unroll
  for (int ni = 0; ni < 4; ++ni) {
    qb[ni] = q0 + wcol * 64 + ni * 16 + ch4;
    const float4 q2 = *reinterpret_cast<const float4*>(&n2[qb[ni]]);
    rnq[ni][0] = __builtin_amdgcn_rcpf(fmaxf(sqrtf(q2.x), 1e-4f));
    rnq[ni][1] = __builtin_amdgcn_rcpf(fmaxf(sqrtf(q2.y), 1e-4f));
    rnq[ni][2] = __builtin_amdgcn_rcpf(fmaxf(sqrtf(q2.z), 1e-4f));
    rnq[ni][3] = __builtin_amdgcn_rcpf(fmaxf(sqrtf(q2.w), 1e-4f));
  }

#pragma unroll
  for (int mi = 0; mi < 4; ++mi) {
    const int pr = p0 + wrow * 64 + mi * 16 + cl;
#pragma unroll
    for (int ni = 0; ni < 4; ++ni) {
      float4 v;
      v.x = acc[mi][ni][0] * rnp[mi] * rnq[ni][0];
      v.y = acc[mi][ni][1] * rnp[mi] * rnq[ni][1];
      v.z = acc[mi][ni][2] * rnp[mi] * rnq[ni][2];
      v.w = acc[mi][ni][3] * rnp[mi] * rnq[ni][3];
      if (tm == tn) {
        if (pr == qb[ni] + 0) v.x = 1.0f;
        if (pr == qb[ni] + 1) v.y = 1.0f;
        if (pr == qb[ni] + 2) v.z = 1.0f;
        if (pr == qb[ni] + 3) v.w = 1.0f;
      }
      *reinterpret_cast<float4*>(&ob[(size_t)pr * P_ + qb[ni]]) = v;
      if (tm != tn) {  // mirrored tile (sim is symmetric; diag never lands here)
        ob[(size_t)(qb[ni] + 0) * P_ + pr] = v.x;
        ob[(size_t)(qb[ni] + 1) * P_ + pr] = v.y;
        ob[(size_t)(qb[ni] + 2) * P_ + pr] = v.z;
        ob[(size_t)(qb[ni] + 3) * P_ + pr] = v.w;
      }
    }
  }
}

extern "C" void kernel_launch(void* const* d_in, const int* in_sizes, int n_in,
                              void* d_out, int out_size, void* d_ws, size_t ws_size,
                              hipStream_t stream) {
  const float* x = (const float*)d_in[0];
  float* out = (float*)d_out;

  // ws: Xt bf16 [16][2048][256] = 16 MB, then nrm2 fp32 [16][2048] = 128 KB
  short* Xt = (short*)d_ws;
  float* nrm2 = (float*)((char*)d_ws + (size_t)B_ * P_ * C_ * sizeof(short));

  hipMemsetAsync(nrm2, 0, (size_t)B_ * P_ * sizeof(float), stream);
  k_transpose<<<dim3(P_ / 32, C_ / 32, B_), dim3(32, 8), 0, stream>>>(x, Xt, nrm2);
  k_gemm<<<dim3(NT_OFF + P_ / 128, B_), 256, 0, stream>>>(Xt, nrm2, out);
}

// Round 6
// 90.750 us; speedup vs baseline: 1.2506x; 1.0967x over previous
//
#include <hip/hip_runtime.h>

#define B_ 16
#define C_ 256
#define P_ 2048
#define BK 32
#define NT 136      // tiles per batch (120 strict-upper + 16 diag)
#define NT_OFF 120

typedef __attribute__((ext_vector_type(8))) short short8;
typedef __attribute__((ext_vector_type(4))) float floatx4;

// round-to-nearest-even fp32 -> bf16
__device__ inline short f2bf(float v) {
  union { float f; unsigned u; } c; c.f = v;
  unsigned r = c.u + 0x7fffu + ((c.u >> 16) & 1u);
  return (short)(r >> 16);
}

#define GLOAD_LDS16(g, l)                                          \
  __builtin_amdgcn_global_load_lds(                                \
      (const __attribute__((address_space(1))) void*)(g),          \
      (__attribute__((address_space(3))) void*)(l), 16, 0, 0)

// ---------------- kernel 1: transpose + fp32->bf16 + norm^2 ----------------
__global__ void k_transpose(const float* __restrict__ x, short* __restrict__ Xt,
                            float* __restrict__ nrm2) {
  __shared__ float t[32][33];
  __shared__ float red[8][32];
  const int p0 = blockIdx.x * 32, c0 = blockIdx.y * 32, b = blockIdx.z;
  const float* xb = x + (size_t)b * C_ * P_;
  short* xtb = Xt + (size_t)b * P_ * C_;
  const int tx = threadIdx.x, ty = threadIdx.y;
  float s = 0.f;
#pragma unroll
  for (int i = 0; i < 4; ++i) {
    float v = xb[(size_t)(c0 + ty + i * 8) * P_ + p0 + tx];
    t[ty + i * 8][tx] = v;
    s += v * v;
  }
  red[ty][tx] = s;
  __syncthreads();
  const int tid = ty * 32 + tx;
  const int r = tid >> 3, ch = tid & 7;
  short4 v;
  v.x = f2bf(t[ch * 4 + 0][r]);
  v.y = f2bf(t[ch * 4 + 1][r]);
  v.z = f2bf(t[ch * 4 + 2][r]);
  v.w = f2bf(t[ch * 4 + 3][r]);
  *reinterpret_cast<short4*>(&xtb[(size_t)(p0 + r) * C_ + c0 + ch * 4]) = v;
  if (tid < 32) {
    float ns = 0.f;
#pragma unroll
    for (int j = 0; j < 8; ++j) ns += red[j][tid];
    atomicAdd(&nrm2[b * P_ + p0 + tid], ns);
  }
}

// ---------------- kernel 2: symmetric Gram GEMM, XCD-chunked ----------------
__global__ __launch_bounds__(256, 3) void k_gemm(const short* __restrict__ Xt,
                                                 const float* __restrict__ nrm2,
                                                 float* __restrict__ out) {
  // XCD-chunked mapping: xcd = bid%8 owns 2 full batches -> Xt working set 2MB, L2-resident
  const int bid = blockIdx.x;
  const int xcd = bid & 7;
  const int s = bid >> 3;              // 0..271
  const int b = xcd * 2 + (s >= NT);   // 2 batches per XCD
  int t = s - (s >= NT ? NT : 0);      // 0..135

  int tm, tn;
  if (t < NT_OFF) {  // strict-upper tiles (2 writes) first
    int rem = t, len = 15;
    tm = 0;
    while (rem >= len) { rem -= len; --len; ++tm; }
    tn = tm + 1 + rem;
  } else {
    tm = tn = t - NT_OFF;
  }
  const int p0 = tm * 128, q0 = tn * 128;
  const short* Xb = Xt + (size_t)b * P_ * C_;

  __shared__ __align__(16) char smem[32768];          // As[2][8K] | Bs[2][8K]
  __shared__ __align__(16) float etile_s[4 * 1280];   // per-wave mirror bounce, 20KB

  const int tid = threadIdx.x;
  const int lane = tid & 63;
  const int wid = tid >> 6;
  const int wrow = wid >> 1;  // p band (64)
  const int wcol = wid & 1;   // q band (64)

  floatx4 acc[4][4];
#pragma unroll
  for (int i = 0; i < 4; ++i)
#pragma unroll
    for (int j = 0; j < 4; ++j) acc[i][j] = (floatx4){0.f, 0.f, 0.f, 0.f};

  const int K2 = C_ * 2;  // row stride bytes

  auto STAGE = [&](int buf, int kt) {
    const int kb = kt * (BK * 2);
#pragma unroll
    for (int j = 0; j < 2; ++j) {
      const int chunk = j * 4 + wid;           // 0..7, wave-uniform
      const int f = chunk * 1024 + lane * 16;
      const int row = f >> 6;
      const int inrow = f & 63;
      GLOAD_LDS16((const char*)Xb + (size_t)(p0 + row) * K2 + kb + inrow,
                  smem + buf * 8192 + chunk * 1024);
      GLOAD_LDS16((const char*)Xb + (size_t)(q0 + row) * K2 + kb + inrow,
                  smem + 16384 + buf * 8192 + chunk * 1024);
    }
  };

  STAGE(0, 0);

  for (int kt = 0; kt < C_ / BK; ++kt) {
    const int cur = kt & 1;
    if (kt < C_ / BK - 1) {
      STAGE(cur ^ 1, kt + 1);
      // my 4 cur-tile loads are the oldest outstanding -> landed after this wait
      asm volatile("s_waitcnt vmcnt(4)\n\ts_barrier" ::: "memory");
    } else {
      asm volatile("s_waitcnt vmcnt(0)\n\ts_barrier" ::: "memory");
    }

    const short* As = (const short*)(smem + cur * 8192);
    const short* Bs = (const short*)(smem + 16384 + cur * 8192);
    short8 af[4], bf[4];
#pragma unroll
    for (int mi = 0; mi < 4; ++mi) {
      const int r = wrow * 64 + mi * 16 + (lane & 15);
      af[mi] = *reinterpret_cast<const short8*>(&As[r * BK + (lane >> 4) * 8]);
    }
#pragma unroll
    for (int ni = 0; ni < 4; ++ni) {
      const int r = wcol * 64 + ni * 16 + (lane & 15);
      bf[ni] = *reinterpret_cast<const short8*>(&Bs[r * BK + (lane >> 4) * 8]);
    }
    // D[row=p][col=q]; C/D layout: col=lane&15, row=(lane>>4)*4+reg (verified r1)
#pragma unroll
    for (int mi = 0; mi < 4; ++mi)
#pragma unroll
      for (int ni = 0; ni < 4; ++ni)
        acc[mi][ni] = __builtin_amdgcn_mfma_f32_16x16x32_bf16(af[mi], bf[ni], acc[mi][ni], 0, 0, 0);

    // ROOT CAUSE of r3-r5 fails: ds_read ISSUE-before-barrier is not COMPLETION.
    // A wave could reach the barrier with buf-cur ds_reads still queued in the LDS
    // pipe (MFMAs + their lgkmcnt waits legally sink below the barrier: register-only
    // ops aren't ordered by the "memory" clobber). The next iteration's
    // global_load_lds restage of buf cur then lands BEFORE those reads execute ->
    // reads return tile kt+2 data. lgkmcnt(0) forces read COMPLETION pre-barrier.
    asm volatile("s_waitcnt lgkmcnt(0)\n\ts_barrier" ::: "memory");
  }

  // ---- epilogue ----
  const float* n2 = nrm2 + (size_t)b * P_;
  float* ob = out + (size_t)b * P_ * P_;
  const int cl = lane & 15, rg4 = (lane >> 4) * 4;

  float rnq[4];
#pragma unroll
  for (int ni = 0; ni < 4; ++ni) {
    const int qc = q0 + wcol * 64 + ni * 16 + cl;
    rnq[ni] = __builtin_amdgcn_rcpf(fmaxf(sqrtf(n2[qc]), 1e-4f));
  }
  floatx4 rnp[4];
#pragma unroll
  for (int mi = 0; mi < 4; ++mi) {
    const float4 p2 = *reinterpret_cast<const float4*>(&n2[p0 + wrow * 64 + mi * 16 + rg4]);
    rnp[mi][0] = __builtin_amdgcn_rcpf(fmaxf(sqrtf(p2.x), 1e-4f));
    rnp[mi][1] = __builtin_amdgcn_rcpf(fmaxf(sqrtf(p2.y), 1e-4f));
    rnp[mi][2] = __builtin_amdgcn_rcpf(fmaxf(sqrtf(p2.z), 1e-4f));
    rnp[mi][3] = __builtin_amdgcn_rcpf(fmaxf(sqrtf(p2.w), 1e-4f));
  }

  // per-wave transposed bounce region: [64 q][20 p] fp32 (own array, intra-wave only)
  float* etile = etile_s + wid * 1280;

#pragma unroll
  for (int mi = 0; mi < 4; ++mi) {
    const int prow = p0 + wrow * 64 + mi * 16 + rg4;
#pragma unroll
    for (int ni = 0; ni < 4; ++ni) {
      floatx4 vv = acc[mi][ni] * rnp[mi] * rnq[ni];
      const int qc = q0 + wcol * 64 + ni * 16 + cl;
      if (tm == tn) {
        const int d = qc - prow;  // diag when prow + r == qc
        if (d >= 0 && d < 4) vv[d] = 1.0f;
      }
      // normal tile: 4 scalar stores, 16 consecutive cols per 16-lane group (64B segs)
      ob[(size_t)(prow + 0) * P_ + qc] = vv[0];
      ob[(size_t)(prow + 1) * P_ + qc] = vv[1];
      ob[(size_t)(prow + 2) * P_ + qc] = vv[2];
      ob[(size_t)(prow + 3) * P_ + qc] = vv[3];
      if (tm != tn)  // stash transposed: lane's 4 consecutive p at row q
        *reinterpret_cast<floatx4*>(&etile[(ni * 16 + cl) * 20 + rg4]) = vv;
    }
    if (tm != tn) {
      // coalesced mirror store for this 16-col (p) slab: rows q, 64B segments
      const int pcb = p0 + wrow * 64 + mi * 16;
#pragma unroll
      for (int i = 0; i < 4; ++i) {
        const int qq = i * 16 + (lane >> 2);
        const floatx4 mv = *reinterpret_cast<const floatx4*>(&etile[qq * 20 + (lane & 3) * 4]);
        *reinterpret_cast<floatx4*>(
            &ob[(size_t)(q0 + wcol * 64 + qq) * P_ + pcb + (lane & 3) * 4]) = mv;
      }
    }
  }
}

extern "C" void kernel_launch(void* const* d_in, const int* in_sizes, int n_in,
                              void* d_out, int out_size, void* d_ws, size_t ws_size,
                              hipStream_t stream) {
  const float* x = (const float*)d_in[0];
  float* out = (float*)d_out;

  short* Xt = (short*)d_ws;                                                    // 16 MB
  float* nrm2 = (float*)((char*)d_ws + (size_t)B_ * P_ * C_ * sizeof(short));  // 128 KB

  hipMemsetAsync(nrm2, 0, (size_t)B_ * P_ * sizeof(float), stream);
  k_transpose<<<dim3(P_ / 32, C_ / 32, B_), dim3(32, 8), 0, stream>>>(x, Xt, nrm2);
  k_gemm<<<dim3(NT * B_), 256, 0, stream>>>(Xt, nrm2, out);
}